// Round 2
// baseline (318.987 us; speedup 1.0000x reference)
//
#include <hip/hip_runtime.h>
#include <math.h>

#define NE 8
#define KDIM 4096
#define PDIM 64
#define WROWS (KDIM + PDIM)   // 4160
#define EPS_F32 1.1920929e-07f
#define NCHUNK 16             // 4096 / (64 lanes * 4 floats)
#define DEPTH 3               // x prefetch depth-2 => 3 register buffer sets

typedef float f4 __attribute__((ext_vector_type(4)));

// --- tiny setup kernel: W[4160][8] -> Wt[8][4160] in d_ws ---
__global__ __launch_bounds__(256)
void transpose_w(const float* __restrict__ W, float* __restrict__ Wt) {
    const int k = blockIdx.x * 256 + threadIdx.x;
    if (k < WROWS) {
        float v[NE];
#pragma unroll
        for (int e = 0; e < NE; ++e) v[e] = W[(size_t)k * NE + e];
#pragma unroll
        for (int e = 0; e < NE; ++e) Wt[(size_t)e * WROWS + k] = v[e];
    }
}

// One wave per block, 4 tokens per wave, FULL K per wave.
// Register diet vs the 206-us baseline: wb is SINGLE-buffered (Wt is
// L2-resident, ~300cy latency, hidden by co-resident waves), only x keeps
// the depth-2 prefetch (HBM latency). ~118 VGPRs -> 4 waves/SIMD
// (__launch_bounds__(64,4)), doubling memory-level parallelism per CU vs
// the baseline's 2 waves/SIMD at ~200 VGPRs.
// Chunk phase stagger kept from baseline: (c + 5*bid) mod 16 spreads
// concurrent waves across the 16KB row period.
__global__ __launch_bounds__(64, 4)
void topk_gate(const float* __restrict__ x,
               const float* __restrict__ prompt,
               const float* __restrict__ Wt,
               const float* __restrict__ b,
               float* __restrict__ out,
               int tokens)
{
    const int lane  = threadIdx.x;      // 0..63
    const int tbase = blockIdx.x * 4;
    const int klane = lane * 4;
    const int phase = (blockIdx.x * 5) & 15;

    float acc[4][NE];
#pragma unroll
    for (int t = 0; t < 4; ++t)
#pragma unroll
        for (int e = 0; e < NE; ++e) acc[t][e] = 0.f;

    // wave-uniform row bases (divergence analysis keeps these in SGPRs)
    const float* xt[4];
#pragma unroll
    for (int t = 0; t < 4; ++t)
        xt[t] = x + (size_t)(tbase + t) * KDIM;
    const float* wrow[NE];
#pragma unroll
    for (int e = 0; e < NE; ++e)
        wrow[e] = Wt + (size_t)e * WROWS;

    f4 xb[DEPTH][4];

    auto load_x = [&](int c, int s) {
        const int k = ((c + phase) & 15) * 256 + klane;
#pragma unroll
        for (int t = 0; t < 4; ++t)
            xb[s][t] = __builtin_nontemporal_load((const f4*)(xt[t] + k));
    };

    load_x(0, 0);
    load_x(1, 1);

#pragma unroll
    for (int c = 0; c < NCHUNK; ++c) {
        // Wt loads for the CURRENT chunk, single-buffered (issued before the
        // x prefetch so the pre-FMA wait is vmcnt(4), not a full drain).
        const int kw = ((c + phase) & 15) * 256 + klane;
        f4 wb[NE];
#pragma unroll
        for (int e = 0; e < NE; ++e)
            wb[e] = *(const f4*)(wrow[e] + kw);

        if (c + 2 < NCHUNK) load_x(c + 2, (c + 2) % DEPTH);

        const int s = c % DEPTH;
#pragma unroll
        for (int t = 0; t < 4; ++t)
#pragma unroll
            for (int e = 0; e < NE; ++e) {
                acc[t][e] = fmaf(xb[s][t].x, wb[e].x, acc[t][e]);
                acc[t][e] = fmaf(xb[s][t].y, wb[e].y, acc[t][e]);
                acc[t][e] = fmaf(xb[s][t].z, wb[e].z, acc[t][e]);
                acc[t][e] = fmaf(xb[s][t].w, wb[e].w, acc[t][e]);
            }
    }

    // prompt part (64 dims): lanes 0..15, contiguous Wt rows 4096..4159
    if (lane < 16) {
        const int k = lane * 4;
        f4 pv[4];
#pragma unroll
        for (int t = 0; t < 4; ++t)
            pv[t] = *(const f4*)(prompt + (size_t)(tbase + t) * PDIM + k);
        f4 wv[NE];
#pragma unroll
        for (int e = 0; e < NE; ++e)
            wv[e] = *(const f4*)(Wt + (size_t)e * WROWS + KDIM + k);
#pragma unroll
        for (int t = 0; t < 4; ++t)
#pragma unroll
            for (int e = 0; e < NE; ++e) {
                acc[t][e] = fmaf(pv[t].x, wv[e].x, acc[t][e]);
                acc[t][e] = fmaf(pv[t].y, wv[e].y, acc[t][e]);
                acc[t][e] = fmaf(pv[t].z, wv[e].z, acc[t][e]);
                acc[t][e] = fmaf(pv[t].w, wv[e].w, acc[t][e]);
            }
    }

    // butterfly reduce: every lane ends with full logits for all 4 tokens
#pragma unroll
    for (int t = 0; t < 4; ++t)
#pragma unroll
        for (int e = 0; e < NE; ++e) {
            float v = acc[t][e];
#pragma unroll
            for (int off = 32; off >= 1; off >>= 1)
                v += __shfl_xor(v, off, 64);
            acc[t][e] = v;
        }

    // ---- epilogue: lane = tt*16 + kk*8 + ee -> one mask element per lane ----
    const int tt = lane >> 4;
    const int kk = (lane >> 3) & 1;
    const int ee = lane & 7;

    float lg[NE];
#pragma unroll
    for (int e = 0; e < NE; ++e) {
        float v = acc[0][e];
        if (tt == 1) v = acc[1][e];
        if (tt == 2) v = acc[2][e];
        if (tt == 3) v = acc[3][e];
        lg[e] = v + b[e];
    }

    // top-2, strict > so smallest index wins ties (jax.lax.top_k semantics)
    float v0 = lg[0]; int i0 = 0;
#pragma unroll
    for (int e = 1; e < NE; ++e)
        if (lg[e] > v0) { v0 = lg[e]; i0 = e; }
    float v1 = (i0 == 0) ? lg[1] : lg[0];
    int   i1 = (i0 == 0) ? 1 : 0;
#pragma unroll
    for (int e = 0; e < NE; ++e)
        if (e != i0 && lg[e] > v1) { v1 = lg[e]; i1 = e; }

    float s = 0.f;
#pragma unroll
    for (int e = 0; e < NE; ++e) s += __expf(lg[e] - v0);
    const float g0 = 1.0f / s;
    const float g1 = __expf(v1 - v0) / s;
    const float denom = fmaxf(g0 + g1, EPS_F32);

    const int sel = kk ? i1 : i0;
    const int t_global = tbase + tt;
    out[(size_t)t_global * 16 + kk * 8 + ee] = (ee == sel) ? 1.0f : 0.0f;

    if ((lane & 15) < 2) {
        const float g = (ee == 0) ? (g0 / denom) : (g1 / denom);
        out[(size_t)tokens * 16 + (size_t)t_global * 2 + ee] = g;
    }
}

extern "C" void kernel_launch(void* const* d_in, const int* in_sizes, int n_in,
                              void* d_out, int out_size, void* d_ws, size_t ws_size,
                              hipStream_t stream) {
    const float* x      = (const float*)d_in[0];
    const float* prompt = (const float*)d_in[1];
    const float* W      = (const float*)d_in[2];
    const float* b      = (const float*)d_in[3];
    float* out          = (float*)d_out;
    float* Wt           = (float*)d_ws;          // 8*4160*4 = 133 KB

    const int tokens = in_sizes[0] / KDIM;       // 8192

    hipLaunchKernelGGL(transpose_w, dim3((WROWS + 255) / 256), dim3(256), 0, stream,
                       W, Wt);
    hipLaunchKernelGGL(topk_gate, dim3(tokens / 4), dim3(64), 0, stream,
                       x, prompt, Wt, b, out, tokens);
}

// Round 3
// 215.648 us; speedup vs baseline: 1.4792x; 1.4792x over previous
//
#include <hip/hip_runtime.h>
#include <math.h>

#define NE 8
#define KDIM 4096
#define PDIM 64
#define WROWS (KDIM + PDIM)   // 4160
#define EPS_F32 1.1920929e-07f
#define NCHUNK 16             // 4096 / (64 lanes * 4 floats)
#define TPW 2                 // tokens per wave

typedef float f4 __attribute__((ext_vector_type(4)));

// --- tiny setup kernel: W[4160][8] -> Wt[8][4160] in d_ws ---
__global__ __launch_bounds__(256)
void transpose_w(const float* __restrict__ W, float* __restrict__ Wt) {
    const int k = blockIdx.x * 256 + threadIdx.x;
    if (k < WROWS) {
        float v[NE];
#pragma unroll
        for (int e = 0; e < NE; ++e) v[e] = W[(size_t)k * NE + e];
#pragma unroll
        for (int e = 0; e < NE; ++e) Wt[(size_t)e * WROWS + k] = v[e];
    }
}

// One wave per block, TWO tokens per wave, FULL K per wave.
// Grid = 4096 blocks -> 16 waves/CU = 4 waves/SIMD (the grid, not
// launch_bounds, is what sets occupancy; round-2's 2048-block grid pinned
// us at 2/SIMD). Register budget actually fits the (64,4) unified cap of
// 128: xb 3x2 f4 = 24, wb 2x8 f4 = 64, acc 16, misc ~12 => ~116.
// wb double-buffered and issued BEFORE the x prefetch so the pre-FMA
// vmcnt wait never drains the in-flight x loads (vmcnt is issue-ordered).
// x loads are normal (not NT): 134 MB < 256 MiB L3, so x stays
// Infinity-Cache-resident across timed replays (round-1 pass showed
// FETCH ~3 MB in that regime).
__global__ __launch_bounds__(64, 4)
void topk_gate(const float* __restrict__ x,
               const float* __restrict__ prompt,
               const float* __restrict__ Wt,
               const float* __restrict__ b,
               float* __restrict__ out,
               int tokens)
{
    const int lane  = threadIdx.x;      // 0..63
    const int tbase = blockIdx.x * TPW;
    const int klane = lane * 4;
    const int phase = (blockIdx.x * 5) & 15;

    float acc[TPW][NE];
#pragma unroll
    for (int t = 0; t < TPW; ++t)
#pragma unroll
        for (int e = 0; e < NE; ++e) acc[t][e] = 0.f;

    // wave-uniform row bases (stay in SGPRs; addressing = s-base + v-offset)
    const float* xr0 = x + (size_t)tbase * KDIM;
    const float* xr1 = xr0 + KDIM;
    const float* wr[NE];
#pragma unroll
    for (int e = 0; e < NE; ++e)
        wr[e] = Wt + (size_t)e * WROWS;

    f4 xb[3][TPW];     // x: depth-2 prefetch (3 buffers)
    f4 wb[2][NE];      // w: depth-1 prefetch (2 buffers)

    auto koff = [&](int c) { return ((c + phase) & 15) * 256 + klane; };

    // ---- prologue: w(0), then x(0), x(1) ----
    {
        const int k0 = koff(0);
#pragma unroll
        for (int e = 0; e < NE; ++e)
            wb[0][e] = *(const f4*)(wr[e] + k0);
        xb[0][0] = *(const f4*)(xr0 + k0);
        xb[0][1] = *(const f4*)(xr1 + k0);
        const int k1 = koff(1);
        xb[1][0] = *(const f4*)(xr0 + k1);
        xb[1][1] = *(const f4*)(xr1 + k1);
    }

#pragma unroll
    for (int c = 0; c < NCHUNK; ++c) {
        // issue w(c+1) first ...
        if (c + 1 < NCHUNK) {
            const int kw = koff(c + 1);
#pragma unroll
            for (int e = 0; e < NE; ++e)
                wb[(c + 1) & 1][e] = *(const f4*)(wr[e] + kw);
        }
        // ... then x(c+2), so waiting on wb[c] never drains the x queue
        if (c + 2 < NCHUNK) {
            const int kx = koff(c + 2);
            xb[(c + 2) % 3][0] = *(const f4*)(xr0 + kx);
            xb[(c + 2) % 3][1] = *(const f4*)(xr1 + kx);
        }

        const int s = c % 3;
        const int wv = c & 1;
#pragma unroll
        for (int t = 0; t < TPW; ++t)
#pragma unroll
            for (int e = 0; e < NE; ++e) {
                const f4 xv = xb[s][t];
                acc[t][e] = fmaf(xv.x, wb[wv][e].x, acc[t][e]);
                acc[t][e] = fmaf(xv.y, wb[wv][e].y, acc[t][e]);
                acc[t][e] = fmaf(xv.z, wb[wv][e].z, acc[t][e]);
                acc[t][e] = fmaf(xv.w, wb[wv][e].w, acc[t][e]);
            }
    }

    // prompt part (64 dims): lanes 0..15, contiguous Wt rows 4096..4159
    if (lane < 16) {
        const int k = lane * 4;
        f4 pv[TPW];
#pragma unroll
        for (int t = 0; t < TPW; ++t)
            pv[t] = *(const f4*)(prompt + (size_t)(tbase + t) * PDIM + k);
#pragma unroll
        for (int e = 0; e < NE; ++e) {
            const f4 wv = *(const f4*)(Wt + (size_t)e * WROWS + KDIM + k);
#pragma unroll
            for (int t = 0; t < TPW; ++t) {
                acc[t][e] = fmaf(pv[t].x, wv.x, acc[t][e]);
                acc[t][e] = fmaf(pv[t].y, wv.y, acc[t][e]);
                acc[t][e] = fmaf(pv[t].z, wv.z, acc[t][e]);
                acc[t][e] = fmaf(pv[t].w, wv.w, acc[t][e]);
            }
        }
    }

    // butterfly reduce: every lane ends with full logits for both tokens
#pragma unroll
    for (int t = 0; t < TPW; ++t)
#pragma unroll
        for (int e = 0; e < NE; ++e) {
            float v = acc[t][e];
#pragma unroll
            for (int off = 32; off >= 1; off >>= 1)
                v += __shfl_xor(v, off, 64);
            acc[t][e] = v;
        }

    // ---- epilogue: lanes 0..31, lane = tt*16 + kk*8 + ee ----
    const int tt = (lane >> 4) & 1;
    const int kk = (lane >> 3) & 1;
    const int ee = lane & 7;

    float lg[NE];
#pragma unroll
    for (int e = 0; e < NE; ++e) {
        const float v = (tt == 0) ? acc[0][e] : acc[1][e];
        lg[e] = v + b[e];
    }

    // top-2, strict > so smallest index wins ties (jax.lax.top_k semantics)
    float v0 = lg[0]; int i0 = 0;
#pragma unroll
    for (int e = 1; e < NE; ++e)
        if (lg[e] > v0) { v0 = lg[e]; i0 = e; }
    float v1 = (i0 == 0) ? lg[1] : lg[0];
    int   i1 = (i0 == 0) ? 1 : 0;
#pragma unroll
    for (int e = 0; e < NE; ++e)
        if (e != i0 && lg[e] > v1) { v1 = lg[e]; i1 = e; }

    float s = 0.f;
#pragma unroll
    for (int e = 0; e < NE; ++e) s += __expf(lg[e] - v0);
    const float g0 = 1.0f / s;
    const float g1 = __expf(v1 - v0) / s;
    const float denom = fmaxf(g0 + g1, EPS_F32);

    if (lane < 32) {
        const int sel = kk ? i1 : i0;
        const int t_global = tbase + tt;
        out[(size_t)t_global * 16 + kk * 8 + ee] = (ee == sel) ? 1.0f : 0.0f;

        if ((lane & 15) < 2) {
            const float g = (ee == 0) ? (g0 / denom) : (g1 / denom);
            out[(size_t)tokens * 16 + (size_t)t_global * 2 + ee] = g;
        }
    }
}

extern "C" void kernel_launch(void* const* d_in, const int* in_sizes, int n_in,
                              void* d_out, int out_size, void* d_ws, size_t ws_size,
                              hipStream_t stream) {
    const float* x      = (const float*)d_in[0];
    const float* prompt = (const float*)d_in[1];
    const float* W      = (const float*)d_in[2];
    const float* b      = (const float*)d_in[3];
    float* out          = (float*)d_out;
    float* Wt           = (float*)d_ws;          // 8*4160*4 = 133 KB

    const int tokens = in_sizes[0] / KDIM;       // 8192

    hipLaunchKernelGGL(transpose_w, dim3((WROWS + 255) / 256), dim3(256), 0, stream,
                       W, Wt);
    hipLaunchKernelGGL(topk_gate, dim3(tokens / TPW), dim3(64), 0, stream,
                       x, prompt, Wt, b, out, tokens);
}

// Round 4
// 213.834 us; speedup vs baseline: 1.4918x; 1.0085x over previous
//
#include <hip/hip_runtime.h>
#include <math.h>

#define NE 8
#define KDIM 4096
#define PDIM 64
#define WROWS (KDIM + PDIM)   // 4160
#define EPS_F32 1.1920929e-07f
#define NCHUNK 16             // 4096 / (64 lanes * 4 floats)
#define TPW 2                 // tokens per wave
#define WPB 4                 // waves per block

typedef float f4 __attribute__((ext_vector_type(4)));

// --- tiny setup kernel: W[4160][8] -> Wt[8][4160] in d_ws ---
__global__ __launch_bounds__(256)
void transpose_w(const float* __restrict__ W, float* __restrict__ Wt) {
    const int k = blockIdx.x * 256 + threadIdx.x;
    if (k < WROWS) {
        float v[NE];
#pragma unroll
        for (int e = 0; e < NE; ++e) v[e] = W[(size_t)k * NE + e];
#pragma unroll
        for (int e = 0; e < NE; ++e) Wt[(size_t)e * WROWS + k] = v[e];
    }
}

// R3 per-wave body, unchanged; ONLY delta vs R3: 4 waves share one block
// with a BLOCK-UNIFORM chunk phase. All 4 waves walk the same 8 KB Wt
// slice in the same window -> 3 of 4 waves hit L1 (32 KB holds ~4 chunk
// slices), cutting Wt L2 traffic 545 MB -> ~150 MB. R3 showed Wt traffic
// costs ~wall-time/34.5TB/s (TPW 4->2 doubled it and cost +9 us).
// Occupancy unchanged: 1024 blocks x 4 waves / 256 CU = 4 waves/SIMD.
// Per-wave registers unchanged vs R3: xb 24 + wb 64 + acc 16 + misc < 128.
// x loads normal (not NT): L3 is swept by the 512 MB poison fill between
// replays anyway, so x is a mandatory 134 MB HBM read (21 us floor).
__global__ __launch_bounds__(256, 4)
void topk_gate(const float* __restrict__ x,
               const float* __restrict__ prompt,
               const float* __restrict__ Wt,
               const float* __restrict__ b,
               float* __restrict__ out,
               int tokens)
{
    const int tid   = threadIdx.x;
    const int lane  = tid & 63;          // 0..63
    const int wid   = tid >> 6;          // 0..3
    const int tbase = (blockIdx.x * WPB + wid) * TPW;
    const int klane = lane * 4;
    const int phase = (blockIdx.x * 5) & 15;   // block-uniform -> L1 sharing

    float acc[TPW][NE];
#pragma unroll
    for (int t = 0; t < TPW; ++t)
#pragma unroll
        for (int e = 0; e < NE; ++e) acc[t][e] = 0.f;

    // wave-uniform row bases (stay in SGPRs; addressing = s-base + v-offset)
    const float* xr0 = x + (size_t)tbase * KDIM;
    const float* xr1 = xr0 + KDIM;
    const float* wr[NE];
#pragma unroll
    for (int e = 0; e < NE; ++e)
        wr[e] = Wt + (size_t)e * WROWS;

    f4 xb[3][TPW];     // x: depth-2 prefetch (3 buffers)
    f4 wb[2][NE];      // w: depth-1 prefetch (2 buffers)

    auto koff = [&](int c) { return ((c + phase) & 15) * 256 + klane; };

    // ---- prologue: w(0), then x(0), x(1) ----
    {
        const int k0 = koff(0);
#pragma unroll
        for (int e = 0; e < NE; ++e)
            wb[0][e] = *(const f4*)(wr[e] + k0);
        xb[0][0] = *(const f4*)(xr0 + k0);
        xb[0][1] = *(const f4*)(xr1 + k0);
        const int k1 = koff(1);
        xb[1][0] = *(const f4*)(xr0 + k1);
        xb[1][1] = *(const f4*)(xr1 + k1);
    }

#pragma unroll
    for (int c = 0; c < NCHUNK; ++c) {
        // issue w(c+1) first ...
        if (c + 1 < NCHUNK) {
            const int kw = koff(c + 1);
#pragma unroll
            for (int e = 0; e < NE; ++e)
                wb[(c + 1) & 1][e] = *(const f4*)(wr[e] + kw);
        }
        // ... then x(c+2), so waiting on wb[c] never drains the x queue
        if (c + 2 < NCHUNK) {
            const int kx = koff(c + 2);
            xb[(c + 2) % 3][0] = *(const f4*)(xr0 + kx);
            xb[(c + 2) % 3][1] = *(const f4*)(xr1 + kx);
        }

        const int s = c % 3;
        const int wv = c & 1;
#pragma unroll
        for (int t = 0; t < TPW; ++t)
#pragma unroll
            for (int e = 0; e < NE; ++e) {
                const f4 xv = xb[s][t];
                acc[t][e] = fmaf(xv.x, wb[wv][e].x, acc[t][e]);
                acc[t][e] = fmaf(xv.y, wb[wv][e].y, acc[t][e]);
                acc[t][e] = fmaf(xv.z, wb[wv][e].z, acc[t][e]);
                acc[t][e] = fmaf(xv.w, wb[wv][e].w, acc[t][e]);
            }
    }

    // prompt part (64 dims): lanes 0..15, contiguous Wt rows 4096..4159
    if (lane < 16) {
        const int k = lane * 4;
        f4 pv[TPW];
#pragma unroll
        for (int t = 0; t < TPW; ++t)
            pv[t] = *(const f4*)(prompt + (size_t)(tbase + t) * PDIM + k);
#pragma unroll
        for (int e = 0; e < NE; ++e) {
            const f4 wv = *(const f4*)(Wt + (size_t)e * WROWS + KDIM + k);
#pragma unroll
            for (int t = 0; t < TPW; ++t) {
                acc[t][e] = fmaf(pv[t].x, wv.x, acc[t][e]);
                acc[t][e] = fmaf(pv[t].y, wv.y, acc[t][e]);
                acc[t][e] = fmaf(pv[t].z, wv.z, acc[t][e]);
                acc[t][e] = fmaf(pv[t].w, wv.w, acc[t][e]);
            }
        }
    }

    // butterfly reduce: every lane ends with full logits for both tokens
#pragma unroll
    for (int t = 0; t < TPW; ++t)
#pragma unroll
        for (int e = 0; e < NE; ++e) {
            float v = acc[t][e];
#pragma unroll
            for (int off = 32; off >= 1; off >>= 1)
                v += __shfl_xor(v, off, 64);
            acc[t][e] = v;
        }

    // ---- epilogue: lanes 0..31, lane = tt*16 + kk*8 + ee ----
    const int tt = (lane >> 4) & 1;
    const int kk = (lane >> 3) & 1;
    const int ee = lane & 7;

    float lg[NE];
#pragma unroll
    for (int e = 0; e < NE; ++e) {
        const float v = (tt == 0) ? acc[0][e] : acc[1][e];
        lg[e] = v + b[e];
    }

    // top-2, strict > so smallest index wins ties (jax.lax.top_k semantics)
    float v0 = lg[0]; int i0 = 0;
#pragma unroll
    for (int e = 1; e < NE; ++e)
        if (lg[e] > v0) { v0 = lg[e]; i0 = e; }
    float v1 = (i0 == 0) ? lg[1] : lg[0];
    int   i1 = (i0 == 0) ? 1 : 0;
#pragma unroll
    for (int e = 0; e < NE; ++e)
        if (e != i0 && lg[e] > v1) { v1 = lg[e]; i1 = e; }

    float s = 0.f;
#pragma unroll
    for (int e = 0; e < NE; ++e) s += __expf(lg[e] - v0);
    const float g0 = 1.0f / s;
    const float g1 = __expf(v1 - v0) / s;
    const float denom = fmaxf(g0 + g1, EPS_F32);

    if (lane < 32) {
        const int sel = kk ? i1 : i0;
        const int t_global = tbase + tt;
        out[(size_t)t_global * 16 + kk * 8 + ee] = (ee == sel) ? 1.0f : 0.0f;

        if ((lane & 15) < 2) {
            const float g = (ee == 0) ? (g0 / denom) : (g1 / denom);
            out[(size_t)tokens * 16 + (size_t)t_global * 2 + ee] = g;
        }
    }
}

extern "C" void kernel_launch(void* const* d_in, const int* in_sizes, int n_in,
                              void* d_out, int out_size, void* d_ws, size_t ws_size,
                              hipStream_t stream) {
    const float* x      = (const float*)d_in[0];
    const float* prompt = (const float*)d_in[1];
    const float* W      = (const float*)d_in[2];
    const float* b      = (const float*)d_in[3];
    float* out          = (float*)d_out;
    float* Wt           = (float*)d_ws;          // 8*4160*4 = 133 KB

    const int tokens = in_sizes[0] / KDIM;       // 8192

    hipLaunchKernelGGL(transpose_w, dim3((WROWS + 255) / 256), dim3(256), 0, stream,
                       W, Wt);
    hipLaunchKernelGGL(topk_gate, dim3(tokens / (TPW * WPB)), dim3(256), 0, stream,
                       x, prompt, Wt, b, out, tokens);
}

// Round 5
// 202.448 us; speedup vs baseline: 1.5756x; 1.0562x over previous
//
#include <hip/hip_runtime.h>
#include <math.h>

#define NE 8
#define KDIM 4096
#define PDIM 64
#define WROWS (KDIM + PDIM)   // 4160
#define EPS_F32 1.1920929e-07f
#define NCHUNK 16             // 4096 / (64 lanes * 4 floats)
#define TPW 2                 // tokens per wave
#define WAVES 16              // waves per block (1024 threads)
#define ROWF4 (WROWS / 4)     // 1040 f4 per Wt row
#define LDSF4 (NE * ROWF4)    // 8320 f4 = 133120 B of LDS

typedef float f4 __attribute__((ext_vector_type(4)));

// --- tiny setup kernel: W[4160][8] -> Wt[8][4160] in d_ws ---
__global__ __launch_bounds__(256)
void transpose_w(const float* __restrict__ W, float* __restrict__ Wt) {
    const int k = blockIdx.x * 256 + threadIdx.x;
    if (k < WROWS) {
        float v[NE];
#pragma unroll
        for (int e = 0; e < NE; ++e) v[e] = W[(size_t)k * NE + e];
#pragma unroll
        for (int e = 0; e < NE; ++e) Wt[(size_t)e * WROWS + k] = v[e];
    }
}

// Wt staged in LDS once per block (133 KB < 160 KB LDS/CU; 8-phase GEMM
// precedent shows >64KB static LDS works on gfx950). One 1024-thread block
// per CU (grid 256), 16 waves x 2 tokens = 32 tokens/block.
//   - w reads become conflict-free ds_read_b128 (lgkm queue, short latency,
//     compiler-scheduled) -> the per-chunk vm wait is vmcnt(4) on x ONLY,
//     a true depth-2 prefetch. No more 8-load w burst per chunk in the vm
//     queue, and Wt L2 re-read traffic drops 272-545 MB -> 34 MB total.
//   - x loads are NONTEMPORAL (R0's fastest config): x has zero reuse and
//     NT keeps the 134 MB stream from sweeping L2 (which is what made
//     R3/R4's normal-load variants slower than the NT baseline).
// Register budget: xb 3x2 f4 = 24, wb 8 f4 = 32 (single-buffer: LDS
// latency is covered by 4 waves/SIMD), acc 16, addressing ~20 => ~95,
// real headroom under the 128-reg cap that (1024,4) imposes — both prior
// failures were register-cap violations; this one is not close.
__global__ __launch_bounds__(1024, 4)
void topk_gate(const float* __restrict__ x,
               const float* __restrict__ prompt,
               const float* __restrict__ Wt,
               const float* __restrict__ b,
               float* __restrict__ out,
               int tokens)
{
    __shared__ f4 wlds[LDSF4];          // 133120 B

    const int tid  = threadIdx.x;
    const int lane = tid & 63;          // 0..63
    const int wid  = tid >> 6;          // 0..15

    // ---- stage Wt -> LDS (linear f4 copy, coalesced, conflict-free) ----
    {
        const f4* wt4 = (const f4*)Wt;
        for (int i = tid; i < LDSF4; i += WAVES * 64)
            wlds[i] = wt4[i];
    }
    __syncthreads();

    const int tbase = (blockIdx.x * WAVES + wid) * TPW;
    const int phase = (blockIdx.x * 5) & 15;

    float acc[TPW][NE];
#pragma unroll
    for (int t = 0; t < TPW; ++t)
#pragma unroll
        for (int e = 0; e < NE; ++e) acc[t][e] = 0.f;

    const f4* xr0 = (const f4*)(x + (size_t)tbase * KDIM);
    const f4* xr1 = (const f4*)(x + (size_t)(tbase + 1) * KDIM);

    f4 xb[3][TPW];     // x: depth-2 prefetch (3 buffers)

    auto cidx = [&](int c) { return ((c + phase) & 15) * 64 + lane; };  // f4 units

    // ---- prologue: x(0), x(1) ----
    {
        const int k0 = cidx(0);
        xb[0][0] = __builtin_nontemporal_load(xr0 + k0);
        xb[0][1] = __builtin_nontemporal_load(xr1 + k0);
        const int k1 = cidx(1);
        xb[1][0] = __builtin_nontemporal_load(xr0 + k1);
        xb[1][1] = __builtin_nontemporal_load(xr1 + k1);
    }

#pragma unroll
    for (int c = 0; c < NCHUNK; ++c) {
        // x(c+2) issued first: the only vm-queue traffic, so the FMA's
        // wait on x(c) is vmcnt(4) with x(c+1),x(c+2) still in flight.
        if (c + 2 < NCHUNK) {
            const int kx = cidx(c + 2);
            xb[(c + 2) % 3][0] = __builtin_nontemporal_load(xr0 + kx);
            xb[(c + 2) % 3][1] = __builtin_nontemporal_load(xr1 + kx);
        }

        // w for the CURRENT chunk from LDS (8x ds_read_b128, lanes
        // contiguous 16B -> conflict-free; compiler inserts lgkmcnt)
        const int kw = cidx(c);
        f4 wb[NE];
#pragma unroll
        for (int e = 0; e < NE; ++e)
            wb[e] = wlds[e * ROWF4 + kw];

        const int s = c % 3;
#pragma unroll
        for (int t = 0; t < TPW; ++t)
#pragma unroll
            for (int e = 0; e < NE; ++e) {
                const f4 xv = xb[s][t];
                acc[t][e] = fmaf(xv.x, wb[e].x, acc[t][e]);
                acc[t][e] = fmaf(xv.y, wb[e].y, acc[t][e]);
                acc[t][e] = fmaf(xv.z, wb[e].z, acc[t][e]);
                acc[t][e] = fmaf(xv.w, wb[e].w, acc[t][e]);
            }
    }

    // prompt part (64 dims): lanes 0..15, w from LDS f4 cols 1024..1039
    if (lane < 16) {
        f4 pv[TPW];
#pragma unroll
        for (int t = 0; t < TPW; ++t)
            pv[t] = *((const f4*)(prompt + (size_t)(tbase + t) * PDIM) + lane);
#pragma unroll
        for (int e = 0; e < NE; ++e) {
            const f4 wv = wlds[e * ROWF4 + (KDIM / 4) + lane];
#pragma unroll
            for (int t = 0; t < TPW; ++t) {
                acc[t][e] = fmaf(pv[t].x, wv.x, acc[t][e]);
                acc[t][e] = fmaf(pv[t].y, wv.y, acc[t][e]);
                acc[t][e] = fmaf(pv[t].z, wv.z, acc[t][e]);
                acc[t][e] = fmaf(pv[t].w, wv.w, acc[t][e]);
            }
        }
    }

    // butterfly reduce: every lane ends with full logits for both tokens
#pragma unroll
    for (int t = 0; t < TPW; ++t)
#pragma unroll
        for (int e = 0; e < NE; ++e) {
            float v = acc[t][e];
#pragma unroll
            for (int off = 32; off >= 1; off >>= 1)
                v += __shfl_xor(v, off, 64);
            acc[t][e] = v;
        }

    // ---- epilogue: lanes 0..31, lane = tt*16 + kk*8 + ee ----
    const int tt = (lane >> 4) & 1;
    const int kk = (lane >> 3) & 1;
    const int ee = lane & 7;

    float lg[NE];
#pragma unroll
    for (int e = 0; e < NE; ++e) {
        const float v = (tt == 0) ? acc[0][e] : acc[1][e];
        lg[e] = v + b[e];
    }

    // top-2, strict > so smallest index wins ties (jax.lax.top_k semantics)
    float v0 = lg[0]; int i0 = 0;
#pragma unroll
    for (int e = 1; e < NE; ++e)
        if (lg[e] > v0) { v0 = lg[e]; i0 = e; }
    float v1 = (i0 == 0) ? lg[1] : lg[0];
    int   i1 = (i0 == 0) ? 1 : 0;
#pragma unroll
    for (int e = 0; e < NE; ++e)
        if (e != i0 && lg[e] > v1) { v1 = lg[e]; i1 = e; }

    float s = 0.f;
#pragma unroll
    for (int e = 0; e < NE; ++e) s += __expf(lg[e] - v0);
    const float g0 = 1.0f / s;
    const float g1 = __expf(v1 - v0) / s;
    const float denom = fmaxf(g0 + g1, EPS_F32);

    if (lane < 32) {
        const int sel = kk ? i1 : i0;
        const int t_global = tbase + tt;
        out[(size_t)t_global * 16 + kk * 8 + ee] = (ee == sel) ? 1.0f : 0.0f;

        if ((lane & 15) < 2) {
            const float g = (ee == 0) ? (g0 / denom) : (g1 / denom);
            out[(size_t)tokens * 16 + (size_t)t_global * 2 + ee] = g;
        }
    }
}

extern "C" void kernel_launch(void* const* d_in, const int* in_sizes, int n_in,
                              void* d_out, int out_size, void* d_ws, size_t ws_size,
                              hipStream_t stream) {
    const float* x      = (const float*)d_in[0];
    const float* prompt = (const float*)d_in[1];
    const float* W      = (const float*)d_in[2];
    const float* b      = (const float*)d_in[3];
    float* out          = (float*)d_out;
    float* Wt           = (float*)d_ws;          // 8*4160*4 = 133 KB

    const int tokens = in_sizes[0] / KDIM;       // 8192

    hipLaunchKernelGGL(transpose_w, dim3((WROWS + 255) / 256), dim3(256), 0, stream,
                       W, Wt);
    hipLaunchKernelGGL(topk_gate, dim3(tokens / (WAVES * TPW)), dim3(WAVES * 64),
                       0, stream, x, prompt, Wt, b, out, tokens);
}